// Round 1
// baseline (3832.361 us; speedup 1.0000x reference)
//
#include <hip/hip_runtime.h>
#include <hip/hip_bf16.h>
#include <math.h>

// Problem constants (B,T,D,H,O) = (1024, 512, 64, 64, 32)
#define BB 1024
#define TT 512
#define DD 64
#define HH 64
#define NG 256   // 4*H gates
#define OO 32
#define GG 4     // batch rows per block

__device__ __forceinline__ float sigmoid_f(float x) {
    return 1.0f / (1.0f + __expf(-x));
}
__device__ __forceinline__ float tanh_f(float x) {
    // tanh(x) = 1 - 2/(exp(2x)+1); saturates correctly at +/-inf
    return 1.0f - 2.0f / (__expf(2.0f * x) + 1.0f);
}

// One LSTM layer. Each block owns GG batch rows for the whole T loop.
// Thread t (0..255) computes gate t for all GG rows (weights in VGPRs),
// then switches role to pointwise thread (row = t>>6, unit = t&63).
// IN_BF16: input sequence is bf16 (layer-1 reads workspace h0).
// DO_FC: apply final fc + softplus at t == TT-1.
template<bool IN_BF16, bool DO_FC>
__global__ __launch_bounds__(256)
void lstm_layer(const void* __restrict__ xin,          // [B][T][DD] fp32 or bf16
                const float* __restrict__ w_ih,        // [NG][DD]
                const float* __restrict__ w_hh,        // [NG][HH]
                const float* __restrict__ b_ih,        // [NG]
                const float* __restrict__ b_hh,        // [NG]
                __hip_bfloat16* __restrict__ h_out,    // [B][T][HH] bf16 or null
                const float* __restrict__ fc_w,        // [OO][HH]
                const float* __restrict__ fc_b,        // [OO]
                float* __restrict__ out)               // [B][OO]
{
    __shared__ float x_sh[GG][DD];
    __shared__ float h_sh[GG][HH];
    __shared__ float gates_sh[GG][NG];

    const int tid = threadIdx.x;          // == gate id
    const int b0  = blockIdx.x * GG;

    // ---- load this gate's weight rows into registers (once) ----
    float wih[DD], whh[HH];
#pragma unroll
    for (int k = 0; k < DD; k += 4) {
        const float4 a = *(const float4*)(w_ih + (size_t)tid * DD + k);
        wih[k] = a.x; wih[k+1] = a.y; wih[k+2] = a.z; wih[k+3] = a.w;
        const float4 b = *(const float4*)(w_hh + (size_t)tid * HH + k);
        whh[k] = b.x; whh[k+1] = b.y; whh[k+2] = b.z; whh[k+3] = b.w;
    }
    const float bias = b_ih[tid] + b_hh[tid];

    // pointwise identity
    const int pr = tid >> 6, pj = tid & 63;
    float c_reg = 0.0f;

    // x staging identity
    const int xr = tid >> 6, xd = tid & 63;
    const size_t xbase = ((size_t)(b0 + xr) * TT) * DD + xd;

    // h starts at zero
    ((float*)h_sh)[tid] = 0.0f;

    // prefetch x[t=0]
    float xreg;
    if (IN_BF16) xreg = __bfloat162float(((const __hip_bfloat16*)xin)[xbase]);
    else         xreg = ((const float*)xin)[xbase];

    __syncthreads();

    for (int t = 0; t < TT; ++t) {
        // stage x_t, prefetch x_{t+1} (latency hidden behind MAC phase)
        x_sh[xr][xd] = xreg;
        if (t + 1 < TT) {
            const size_t idx = xbase + (size_t)(t + 1) * DD;
            if (IN_BF16) xreg = __bfloat162float(((const __hip_bfloat16*)xin)[idx]);
            else         xreg = ((const float*)xin)[idx];
        }
        __syncthreads();   // x_sh + h_sh ready

        // ---- MAC: acc[r] = bias + w_ih[g].x_t[r] + w_hh[g].h[r] ----
        float acc[GG];
#pragma unroll
        for (int r = 0; r < GG; ++r) acc[r] = bias;
#pragma unroll
        for (int k = 0; k < DD; k += 4) {
#pragma unroll
            for (int r = 0; r < GG; ++r) {
                const float4 xv = *(const float4*)&x_sh[r][k];   // wave-broadcast
                acc[r] = fmaf(wih[k+0], xv.x, acc[r]);
                acc[r] = fmaf(wih[k+1], xv.y, acc[r]);
                acc[r] = fmaf(wih[k+2], xv.z, acc[r]);
                acc[r] = fmaf(wih[k+3], xv.w, acc[r]);
                const float4 hv = *(const float4*)&h_sh[r][k];   // wave-broadcast
                acc[r] = fmaf(whh[k+0], hv.x, acc[r]);
                acc[r] = fmaf(whh[k+1], hv.y, acc[r]);
                acc[r] = fmaf(whh[k+2], hv.z, acc[r]);
                acc[r] = fmaf(whh[k+3], hv.w, acc[r]);
            }
        }
#pragma unroll
        for (int r = 0; r < GG; ++r) gates_sh[r][tid] = acc[r];
        __syncthreads();   // gates ready; MAC reads of h_sh complete

        // ---- pointwise LSTM cell (PyTorch gate order i,f,g,o) ----
        {
            const float gi = gates_sh[pr][pj];
            const float gf = gates_sh[pr][pj + 64];
            const float gg = gates_sh[pr][pj + 128];
            const float go = gates_sh[pr][pj + 192];
            c_reg = sigmoid_f(gf) * c_reg + sigmoid_f(gi) * tanh_f(gg);
            const float hN = sigmoid_f(go) * tanh_f(c_reg);
            h_sh[pr][pj] = hN;   // safe: all MAC reads done (barrier above)
            if (h_out != nullptr)
                h_out[((size_t)(b0 + pr) * TT + t) * HH + pj] = __float2bfloat16(hN);
        }

        if (DO_FC && t == TT - 1) {
            __syncthreads();   // h_sh final values visible
            if (tid < GG * OO) {
                const int r = tid >> 5, o = tid & 31;
                float a = fc_b[o];
#pragma unroll
                for (int j = 0; j < HH; ++j)
                    a = fmaf(fc_w[o * HH + j], h_sh[r][j], a);
                // numerically stable softplus
                out[(size_t)(b0 + r) * OO + o] =
                    fmaxf(a, 0.0f) + log1pf(__expf(-fabsf(a)));
            }
        }
    }
}

extern "C" void kernel_launch(void* const* d_in, const int* in_sizes, int n_in,
                              void* d_out, int out_size, void* d_ws, size_t ws_size,
                              hipStream_t stream) {
    const float* x     = (const float*)d_in[0];
    const float* w_ih0 = (const float*)d_in[1];
    const float* w_hh0 = (const float*)d_in[2];
    const float* b_ih0 = (const float*)d_in[3];
    const float* b_hh0 = (const float*)d_in[4];
    const float* w_ih1 = (const float*)d_in[5];
    const float* w_hh1 = (const float*)d_in[6];
    const float* b_ih1 = (const float*)d_in[7];
    const float* b_hh1 = (const float*)d_in[8];
    const float* fc_w  = (const float*)d_in[9];
    const float* fc_b  = (const float*)d_in[10];
    float* out = (float*)d_out;

    // workspace: h0 (B,T,H) bf16 = 64 MB
    __hip_bfloat16* h0 = (__hip_bfloat16*)d_ws;

    dim3 grid(BB / GG), block(256);
    lstm_layer<false, false><<<grid, block, 0, stream>>>(
        x, w_ih0, w_hh0, b_ih0, b_hh0, h0, nullptr, nullptr, nullptr);
    lstm_layer<true, true><<<grid, block, 0, stream>>>(
        h0, w_ih1, w_hh1, b_ih1, b_hh1, nullptr, fc_w, fc_b, out);
}

// Round 2
// 1428.422 us; speedup vs baseline: 2.6829x; 2.6829x over previous
//
#include <hip/hip_runtime.h>
#include <hip/hip_bf16.h>
#include <math.h>

// (B,T,D,H,O) = (1024, 512, 64, 64, 32)
#define BB 1024
#define TT 512
#define OO 32
#define MM 16              // batch rows per block
#define NBLK (BB/MM)       // 64 blocks

typedef __attribute__((ext_vector_type(8))) short short8;   // 8 bf16 (4 VGPRs)
typedef __attribute__((ext_vector_type(4))) float f32x4;    // MFMA C/D

__device__ __forceinline__ float sigf(float x)  { return 1.0f / (1.0f + __expf(-x)); }
__device__ __forceinline__ float tanhf_(float x){ return 1.0f - 2.0f / (__expf(2.0f * x) + 1.0f); }

// fp32 -> bf16 RNE, bit-level (no API ambiguity)
__device__ __forceinline__ ushort f2bf(float f) {
    union { float f; unsigned u; } v; v.f = f;
    unsigned r = v.u + 0x7FFF + ((v.u >> 16) & 1);
    return (ushort)(r >> 16);
}
__device__ __forceinline__ float bf2f(ushort u) {
    union { unsigned u; float f; } v; v.u = ((unsigned)u) << 16; return v.f;
}

// One LSTM layer on MFMA. Block owns MM=16 batch rows for the whole T loop.
// Per step: gates[16,256] = [x_t | h] (16x128) @ [w_ih | w_hh]^T (128x256),
// via 16x16x32 bf16 MFMA. Wave w owns gate columns {64g + 16w + lane15}:
// i,f,g,o of one (row,unit) share a lane+reg -> pointwise stays in registers.
// Weights live in registers as B-fragments (16 x short8 = 64 VGPRs/wave).
template<bool IN_BF16, bool WRITE_H, bool DO_FC>
__global__ __launch_bounds__(256, 1)
void lstm_mfma(const void* __restrict__ xin,        // [B][T][64] fp32 or bf16
               const float* __restrict__ w_ih,      // [256][64]
               const float* __restrict__ w_hh,      // [256][64]
               const float* __restrict__ b_ih,      // [256]
               const float* __restrict__ b_hh,      // [256]
               ushort* __restrict__ h_out,          // [B][T][64] bf16 (layer0)
               const float* __restrict__ fc_w,      // [32][64]
               const float* __restrict__ fc_b,      // [32]
               float* __restrict__ out)             // [B][32]
{
    // Row stride 72 ushorts = 144 B: keeps 16B alignment for ds_read_b128 and
    // rotates banks by 4/row so the 4-row scattered h-writes don't 4-way conflict.
    __shared__ ushort xs[2][MM][72];   // double-buffered x_t (bf16)
    __shared__ ushort hs[MM][72];      // h_t (bf16)

    const int tid  = threadIdx.x;
    const int wv   = tid >> 6;         // wave 0..3
    const int ln   = tid & 63;
    const int l15  = ln & 15;
    const int quad = ln >> 4;
    const int b0   = blockIdx.x * MM;

    // ---- one-time: weight B-fragments + bias (registers) ----
    // B[k][n] fragment for 16x16x32: lane holds k = quad*8+j, n = l15.
    short8 bfrag[4][4];                // [gate g][k-tile]
    float  biasv[4];
#pragma unroll
    for (int g = 0; g < 4; ++g) {
        const int col = 64 * g + 16 * wv + l15;
        biasv[g] = b_ih[col] + b_hh[col];
#pragma unroll
        for (int kt = 0; kt < 4; ++kt) {
            const int kb = kt * 32 + quad * 8;     // global k in [0,128)
            const float* src = (kb < 64) ? (w_ih + col * 64 + kb)
                                         : (w_hh + col * 64 + (kb - 64));
            const float4 v0 = *(const float4*)src;
            const float4 v1 = *(const float4*)(src + 4);
            short8 b;
            b[0] = (short)f2bf(v0.x); b[1] = (short)f2bf(v0.y);
            b[2] = (short)f2bf(v0.z); b[3] = (short)f2bf(v0.w);
            b[4] = (short)f2bf(v1.x); b[5] = (short)f2bf(v1.y);
            b[6] = (short)f2bf(v1.z); b[7] = (short)f2bf(v1.w);
            bfrag[g][kt] = b;
        }
    }

    // ---- x staging identity: thread -> (row, 4 units) ----
    const int srow = tid >> 4;              // 0..15
    const int su   = (tid & 15) * 4;        // 0,4,...,60
    const size_t sbase = ((size_t)(b0 + srow) * TT) * 64 + su;

    float4 fA, fB; ushort4 uA, uB;
    auto loadx = [&](int t, float4& fr, ushort4& ur) {
        if (IN_BF16) ur = *(const ushort4*)((const ushort*)xin + sbase + (size_t)t * 64);
        else         fr = *(const float4*)((const float*)xin + sbase + (size_t)t * 64);
    };
    auto store_lds = [&](int buf, const float4& fr, const ushort4& ur) {
        ushort4 p;
        if (IN_BF16) p = ur;
        else { p.x = f2bf(fr.x); p.y = f2bf(fr.y); p.z = f2bf(fr.z); p.w = f2bf(fr.w); }
        *(ushort4*)&xs[buf][srow][su] = p;
    };

    // prologue: xs[0] <- t0; regs A <- t1, B <- t2 (prefetch distance 2)
    loadx(0, fA, uA);
    store_lds(0, fA, uA);
    loadx(1, fA, uA);
    loadx(2, fB, uB);
    for (int i = tid; i < MM * 72; i += 256) ((ushort*)hs)[i] = 0;
    float c[4] = {0.f, 0.f, 0.f, 0.f};
    __syncthreads();

    const int hq = 16 * wv + l15;          // this lane's h unit column

    for (int t = 0; t < TT; ++t) {
        const int cur = t & 1;

        // phase 1: stage x_{t+1} into the other buffer; prefetch x_{t+3}
        if (t + 1 < TT) {
            if ((t & 1) == 0) { store_lds(cur ^ 1, fA, uA); if (t + 3 < TT) loadx(t + 3, fA, uA); }
            else              { store_lds(cur ^ 1, fB, uB); if (t + 3 < TT) loadx(t + 3, fB, uB); }
        }

        // phase 2: A-fragments. A[m][k]: m = l15, k = quad*8+j. k<64 from x, else h.
        const short8 a0 = *(const short8*)&xs[cur][l15][quad * 8];
        const short8 a1 = *(const short8*)&xs[cur][l15][32 + quad * 8];
        const short8 a2 = *(const short8*)&hs[l15][quad * 8];
        const short8 a3 = *(const short8*)&hs[l15][32 + quad * 8];

        // phase 3: 16 MFMAs; acc init = bias (b_ih + b_hh broadcast per column)
        f32x4 acc[4];
#pragma unroll
        for (int g = 0; g < 4; ++g) {
            f32x4 a = {biasv[g], biasv[g], biasv[g], biasv[g]};
            a = __builtin_amdgcn_mfma_f32_16x16x32_bf16(a0, bfrag[g][0], a, 0, 0, 0);
            a = __builtin_amdgcn_mfma_f32_16x16x32_bf16(a1, bfrag[g][1], a, 0, 0, 0);
            a = __builtin_amdgcn_mfma_f32_16x16x32_bf16(a2, bfrag[g][2], a, 0, 0, 0);
            a = __builtin_amdgcn_mfma_f32_16x16x32_bf16(a3, bfrag[g][3], a, 0, 0, 0);
            acc[g] = a;
        }

        __syncthreads();   // all waves' A-frag reads done -> safe to overwrite hs

        // phase 4: pointwise cell, fully in registers.
        // C/D layout: col = l15 (-> unit hq), row = quad*4 + r.
#pragma unroll
        for (int r = 0; r < 4; ++r) {
            const float gi = acc[0][r], gf = acc[1][r], gg = acc[2][r], go = acc[3][r];
            c[r] = sigf(gf) * c[r] + sigf(gi) * tanhf_(gg);
            const float h = sigf(go) * tanhf_(c[r]);
            const int row = quad * 4 + r;
            const ushort hb = f2bf(h);
            hs[row][hq] = hb;
            if (WRITE_H)
                h_out[((size_t)(b0 + row) * TT + t) * 64 + hq] = hb;
        }

        __syncthreads();   // hs ready for next step
    }

    if (DO_FC) {
        // hs holds h_{T-1}; 512 outputs, 2 per thread
        for (int idx = tid; idx < MM * OO; idx += 256) {
            const int row = idx >> 5, o = idx & 31;
            float a = fc_b[o];
#pragma unroll
            for (int j = 0; j < 64; ++j)
                a = fmaf(fc_w[o * 64 + j], bf2f(hs[row][j]), a);
            out[(size_t)(b0 + row) * OO + o] =
                fmaxf(a, 0.0f) + log1pf(__expf(-fabsf(a)));   // stable softplus
        }
    }
}

extern "C" void kernel_launch(void* const* d_in, const int* in_sizes, int n_in,
                              void* d_out, int out_size, void* d_ws, size_t ws_size,
                              hipStream_t stream) {
    const float* x     = (const float*)d_in[0];
    const float* w_ih0 = (const float*)d_in[1];
    const float* w_hh0 = (const float*)d_in[2];
    const float* b_ih0 = (const float*)d_in[3];
    const float* b_hh0 = (const float*)d_in[4];
    const float* w_ih1 = (const float*)d_in[5];
    const float* w_hh1 = (const float*)d_in[6];
    const float* b_ih1 = (const float*)d_in[7];
    const float* b_hh1 = (const float*)d_in[8];
    const float* fc_w  = (const float*)d_in[9];
    const float* fc_b  = (const float*)d_in[10];
    float* out = (float*)d_out;

    ushort* h1 = (ushort*)d_ws;   // [B][T][64] bf16 = 64 MB

    lstm_mfma<false, true, false><<<dim3(NBLK), dim3(256), 0, stream>>>(
        x, w_ih0, w_hh0, b_ih0, b_hh0, h1, nullptr, nullptr, nullptr);
    lstm_mfma<true, false, true><<<dim3(NBLK), dim3(256), 0, stream>>>(
        h1, w_ih1, w_hh1, b_ih1, b_hh1, nullptr, fc_w, fc_b, out);
}

// Round 3
// 1251.354 us; speedup vs baseline: 3.0626x; 1.1415x over previous
//
#include <hip/hip_runtime.h>
#include <hip/hip_bf16.h>
#include <math.h>

// (B,T,D,H,O) = (1024, 512, 64, 64, 32)
#define BB 1024
#define TT 512
#define OO 32
#define MM 16              // batch rows per block
#define NBLK (BB/MM)       // 64 blocks

typedef __attribute__((ext_vector_type(8))) short short8;   // 8 bf16 (4 VGPRs)
typedef __attribute__((ext_vector_type(4))) float f32x4;    // MFMA C/D

// Raw barrier: waits LDS ops only (cross-wave hazard is hs in LDS), leaves
// global loads/stores in flight -> no vmcnt(0) drain of the x prefetch.
#define BAR() asm volatile("s_waitcnt lgkmcnt(0)\n\ts_barrier" ::: "memory")

__device__ __forceinline__ float sigf(float x) {
    return __builtin_amdgcn_rcpf(1.0f + __expf(-x));
}
__device__ __forceinline__ float tanhf_(float x) {
    return 1.0f - 2.0f * __builtin_amdgcn_rcpf(__expf(2.0f * x) + 1.0f);
}

// fp32 -> bf16 RNE (used once for weights / h)
__device__ __forceinline__ ushort f2bf(float f) {
    union { float f; unsigned u; } v; v.f = f;
    unsigned r = v.u + 0x7FFF + ((v.u >> 16) & 1);
    return (ushort)(r >> 16);
}
__device__ __forceinline__ float bf2f(ushort u) {
    union { unsigned u; float f; } v; v.u = ((unsigned)u) << 16; return v.f;
}
// pack two fp32 -> bf16x2 (round-to-nearest, ties away): 3 instrs via v_perm
__device__ __forceinline__ unsigned pkbf(float a, float b) {
    union { float f; unsigned u; } x, y; x.f = a; y.f = b;
    return __builtin_amdgcn_perm(y.u + 0x8000u, x.u + 0x8000u, 0x07060302u);
}
__device__ __forceinline__ short8 pack8(const float4& a, const float4& b) {
    union { unsigned u[4]; short8 s; } r;
    r.u[0] = pkbf(a.x, a.y); r.u[1] = pkbf(a.z, a.w);
    r.u[2] = pkbf(b.x, b.y); r.u[3] = pkbf(b.z, b.w);
    return r.s;
}

// Recurrent LSTM layer on MFMA. Block owns MM=16 batch rows for all T.
// gates[16,256] = [x_t | h] (16x128) @ [w_ih | w_hh]^T, 16x16x32 bf16 MFMA.
// Wave w owns gate cols {64g + 16w + lane15} -> i,f,g,o of one (row,unit)
// share a lane+reg -> pointwise in registers. Weights = B-frags in VGPRs.
// h double-buffered in LDS -> 1 raw barrier per step.
template<bool IN_BF16, bool WRITE_H, bool DO_FC>
__global__ __launch_bounds__(256, 1)
void lstm_rec(const void* __restrict__ xin,        // [B][T][64] fp32 or bf16
              const float* __restrict__ w_ih,      // [256][64]
              const float* __restrict__ w_hh,      // [256][64]
              const float* __restrict__ b_ih,      // [256]
              const float* __restrict__ b_hh,      // [256]
              ushort* __restrict__ h_out,          // [B][T][64] bf16 (layer0)
              const float* __restrict__ fc_w,      // [32][64]
              const float* __restrict__ fc_b,      // [32]
              float* __restrict__ out)             // [B][32]
{
    // stride 72 ushorts: 16B-aligned rows, 2-way-max bank aliasing (free)
    __shared__ ushort hs[2][MM][72];

    const int tid  = threadIdx.x;
    const int wv   = tid >> 6;
    const int ln   = tid & 63;
    const int l15  = ln & 15;
    const int quad = ln >> 4;
    const int b0   = blockIdx.x * MM;

    // ---- one-time: weight B-fragments + bias ----
    // B[k][n] frag for 16x16x32: lane holds k = quad*8+j, n = l15.
    short8 bfrag[4][4];                // [gate][ktile], K=128 = x(0:64)|h(64:128)
    float  biasv[4];
#pragma unroll
    for (int g = 0; g < 4; ++g) {
        const int col = 64 * g + 16 * wv + l15;
        biasv[g] = b_ih[col] + b_hh[col];
#pragma unroll
        for (int kt = 0; kt < 4; ++kt) {
            const int kb = kt * 32 + quad * 8;
            const float* src = (kb < 64) ? (w_ih + col * 64 + kb)
                                         : (w_hh + col * 64 + (kb - 64));
            const float4 v0 = *(const float4*)src;
            const float4 v1 = *(const float4*)(src + 4);
            short8 b;
            b[0] = (short)f2bf(v0.x); b[1] = (short)f2bf(v0.y);
            b[2] = (short)f2bf(v0.z); b[3] = (short)f2bf(v0.w);
            b[4] = (short)f2bf(v1.x); b[5] = (short)f2bf(v1.y);
            b[6] = (short)f2bf(v1.z); b[7] = (short)f2bf(v1.w);
            bfrag[g][kt] = b;
        }
    }

    // x A-frag base: lane covers row=l15, k = ktile*32 + quad*8 .. +7
    const size_t xoff = ((size_t)(b0 + l15) * TT) * 64 + quad * 8;

    // prefetch slots (scalars -> stay in VGPRs)
    short8 xsA0, xsA1, xsB0, xsB1;
    float4 xfA0, xfA1, xfA2, xfA3, xfB0, xfB1, xfB2, xfB3;

#define ISSUE(t_, S)                                                          \
    if ((t_) < TT) {                                                          \
        if (IN_BF16) {                                                        \
            const ushort* p = (const ushort*)xin + xoff + (size_t)(t_) * 64;  \
            xs##S##0 = *(const short8*)p;                                     \
            xs##S##1 = *(const short8*)(p + 32);                              \
        } else {                                                              \
            const float* p = (const float*)xin + xoff + (size_t)(t_) * 64;    \
            xf##S##0 = *(const float4*)p;        xf##S##1 = *(const float4*)(p + 4);  \
            xf##S##2 = *(const float4*)(p + 32); xf##S##3 = *(const float4*)(p + 36); \
        }                                                                     \
    }

    // zero hs[0]
    for (int i = tid; i < MM * 72; i += 256) ((ushort*)hs)[i] = 0;

    ISSUE(0, A);
    ISSUE(1, B);

    float c0 = 0.f, c1 = 0.f, c2 = 0.f, c3 = 0.f;
    const int hq = 16 * wv + l15;
    BAR();

#define STEP(t_, CUR, NXT, S)                                                 \
    {                                                                         \
        short8 a0, a1;                                                        \
        if (IN_BF16) { a0 = xs##S##0; a1 = xs##S##1; }                        \
        else { a0 = pack8(xf##S##0, xf##S##1); a1 = pack8(xf##S##2, xf##S##3); } \
        const short8 a2 = *(const short8*)&hs[CUR][l15][quad * 8];            \
        const short8 a3 = *(const short8*)&hs[CUR][l15][32 + quad * 8];       \
        ISSUE((t_) + 2, S);                                                   \
        f32x4 acc[4];                                                         \
        _Pragma("unroll")                                                     \
        for (int g = 0; g < 4; ++g) {                                         \
            f32x4 a = {biasv[g], biasv[g], biasv[g], biasv[g]};               \
            a = __builtin_amdgcn_mfma_f32_16x16x32_bf16(a0, bfrag[g][0], a, 0, 0, 0); \
            a = __builtin_amdgcn_mfma_f32_16x16x32_bf16(a1, bfrag[g][1], a, 0, 0, 0); \
            a = __builtin_amdgcn_mfma_f32_16x16x32_bf16(a2, bfrag[g][2], a, 0, 0, 0); \
            a = __builtin_amdgcn_mfma_f32_16x16x32_bf16(a3, bfrag[g][3], a, 0, 0, 0); \
            acc[g] = a;                                                       \
        }                                                                     \
        float* cc[4] = {&c0, &c1, &c2, &c3};                                  \
        _Pragma("unroll")                                                     \
        for (int r = 0; r < 4; ++r) {                                         \
            const float gi = acc[0][r], gf = acc[1][r];                       \
            const float gg = acc[2][r], go = acc[3][r];                       \
            float cv = *cc[r];                                                \
            cv = sigf(gf) * cv + sigf(gi) * tanhf_(gg);                       \
            *cc[r] = cv;                                                      \
            const float h = sigf(go) * tanhf_(cv);                            \
            const int row = quad * 4 + r;                                     \
            const ushort hb = f2bf(h);                                        \
            hs[NXT][row][hq] = hb;                                            \
            if (WRITE_H)                                                      \
                h_out[((size_t)(b0 + row) * TT + (t_)) * 64 + hq] = hb;       \
        }                                                                     \
        BAR();                                                                \
    }

    for (int tb = 0; tb < TT; tb += 2) {
        STEP(tb,     0, 1, A);
        STEP(tb + 1, 1, 0, B);
    }
#undef STEP
#undef ISSUE

    if (DO_FC) {
        // hs[0] holds h_{T-1} (TT even); last BAR made it visible
        for (int idx = tid; idx < MM * OO; idx += 256) {
            const int row = idx >> 5, o = idx & 31;
            float a = fc_b[o];
#pragma unroll
            for (int j = 0; j < 64; ++j)
                a = fmaf(fc_w[o * 64 + j], bf2f(hs[0][row][j]), a);
            out[(size_t)(b0 + row) * OO + o] =
                fmaxf(a, 0.0f) + log1pf(__expf(-fabsf(a)));   // stable softplus
        }
    }
}

extern "C" void kernel_launch(void* const* d_in, const int* in_sizes, int n_in,
                              void* d_out, int out_size, void* d_ws, size_t ws_size,
                              hipStream_t stream) {
    const float* x     = (const float*)d_in[0];
    const float* w_ih0 = (const float*)d_in[1];
    const float* w_hh0 = (const float*)d_in[2];
    const float* b_ih0 = (const float*)d_in[3];
    const float* b_hh0 = (const float*)d_in[4];
    const float* w_ih1 = (const float*)d_in[5];
    const float* w_hh1 = (const float*)d_in[6];
    const float* b_ih1 = (const float*)d_in[7];
    const float* b_hh1 = (const float*)d_in[8];
    const float* fc_w  = (const float*)d_in[9];
    const float* fc_b  = (const float*)d_in[10];
    float* out = (float*)d_out;

    ushort* h1 = (ushort*)d_ws;   // [B][T][64] bf16 = 64 MB

    lstm_rec<false, true, false><<<dim3(NBLK), dim3(256), 0, stream>>>(
        x, w_ih0, w_hh0, b_ih0, b_hh0, h1, nullptr, nullptr, nullptr);
    lstm_rec<true, false, true><<<dim3(NBLK), dim3(256), 0, stream>>>(
        h1, w_ih1, w_hh1, b_ih1, b_hh1, nullptr, fc_w, fc_b, out);
}

// Round 4
// 670.472 us; speedup vs baseline: 5.7159x; 1.8664x over previous
//
#include <hip/hip_runtime.h>
#include <hip/hip_bf16.h>
#include <math.h>

// (B,T,D,H,O) = (1024, 512, 64, 64, 32)
#define BB 1024
#define TT 512
#define OO 32
#define MM 16              // batch rows per block
#define NBLK (BB/MM)       // 64 blocks

typedef __attribute__((ext_vector_type(8))) short short8;   // 8 bf16 (4 VGPRs)
typedef __attribute__((ext_vector_type(4))) float f32x4;    // MFMA C/D

#define MFMA __builtin_amdgcn_mfma_f32_16x16x32_bf16

// Raw barrier: waits LDS ops only; global loads stay in flight (no vmcnt drain).
#define BAR() asm volatile("s_waitcnt lgkmcnt(0)\n\ts_barrier" ::: "memory")

__device__ __forceinline__ float sigf(float x) {
    return __builtin_amdgcn_rcpf(1.0f + __expf(-x));
}
__device__ __forceinline__ float tanhf_(float x) {
    return 1.0f - 2.0f * __builtin_amdgcn_rcpf(__expf(2.0f * x) + 1.0f);
}

// fp32 -> bf16 RNE
__device__ __forceinline__ ushort f2bf(float f) {
    union { float f; unsigned u; } v; v.f = f;
    unsigned r = v.u + 0x7FFF + ((v.u >> 16) & 1);
    return (ushort)(r >> 16);
}
__device__ __forceinline__ float bf2f(ushort u) {
    union { unsigned u; float f; } v; v.u = ((unsigned)u) << 16; return v.f;
}
// pack two fp32 -> bf16x2 via v_perm (round-half-up)
__device__ __forceinline__ unsigned pkbf(float a, float b) {
    union { float f; unsigned u; } x, y; x.f = a; y.f = b;
    return __builtin_amdgcn_perm(y.u + 0x8000u, x.u + 0x8000u, 0x07060302u);
}
__device__ __forceinline__ short8 pack8(const float4& a, const float4& b) {
    union { unsigned u[4]; short8 s; } r;
    r.u[0] = pkbf(a.x, a.y); r.u[1] = pkbf(a.z, a.w);
    r.u[2] = pkbf(b.x, b.y); r.u[3] = pkbf(b.z, b.w);
    return r.s;
}

// Fused 2-layer LSTM. Block owns MM=16 batch rows for all T. Per step t:
// L0 cell for time t and L1 cell for time t-1 are independent given h0(t-1)
// (both read it as A-frags) -> computed together, one barrier per step, no
// global stores in the loop. Weights for BOTH layers live in registers as
// MFMA B-fragments (32 x short8). c-states fp32 in registers.
__global__ __launch_bounds__(256, 1)
void lstm_fused(const float* __restrict__ x,         // [B][T][64] fp32
                const float* __restrict__ w_ih0,     // [256][64]
                const float* __restrict__ w_hh0,     // [256][64]
                const float* __restrict__ b_ih0,     // [256]
                const float* __restrict__ b_hh0,     // [256]
                const float* __restrict__ w_ih1,     // [256][64]
                const float* __restrict__ w_hh1,     // [256][64]
                const float* __restrict__ b_ih1,     // [256]
                const float* __restrict__ b_hh1,     // [256]
                const float* __restrict__ fc_w,      // [32][64]
                const float* __restrict__ fc_b,      // [32]
                float* __restrict__ out)             // [B][32]
{
    // stride 72 ushorts: 16B-aligned rows, max 2-way bank aliasing (free)
    __shared__ ushort h0s[2][MM][72];
    __shared__ ushort h1s[2][MM][72];

    const int tid  = threadIdx.x;
    const int wv   = tid >> 6;
    const int ln   = tid & 63;
    const int l15  = ln & 15;
    const int quad = ln >> 4;
    const int b0   = blockIdx.x * MM;
    const int hq   = 16 * wv + l15;        // this lane's h unit column

    // ---- one-time: weight B-fragments + bias for both layers ----
    // B[k][n] frag (16x16x32): lane holds k = quad*8+j, n = l15.
    // K=128 layout: k<64 -> w_ih (input half), k>=64 -> w_hh (recurrent half).
    short8 bf0[4][4], bf1[4][4];
    float  bias0[4], bias1[4];
    auto load_w = [&](const float* wih, const float* whh,
                      const float* bih, const float* bhh,
                      short8 (&bf)[4][4], float (&bias)[4]) {
#pragma unroll
        for (int g = 0; g < 4; ++g) {
            const int col = 64 * g + 16 * wv + l15;
            bias[g] = bih[col] + bhh[col];
#pragma unroll
            for (int kt = 0; kt < 4; ++kt) {
                const int kb = kt * 32 + quad * 8;
                const float* src = (kb < 64) ? (wih + col * 64 + kb)
                                             : (whh + col * 64 + (kb - 64));
                const float4 v0 = *(const float4*)src;
                const float4 v1 = *(const float4*)(src + 4);
                short8 b;
                b[0] = (short)f2bf(v0.x); b[1] = (short)f2bf(v0.y);
                b[2] = (short)f2bf(v0.z); b[3] = (short)f2bf(v0.w);
                b[4] = (short)f2bf(v1.x); b[5] = (short)f2bf(v1.y);
                b[6] = (short)f2bf(v1.z); b[7] = (short)f2bf(v1.w);
                bf[g][kt] = b;
            }
        }
    };
    load_w(w_ih0, w_hh0, b_ih0, b_hh0, bf0, bias0);
    load_w(w_ih1, w_hh1, b_ih1, b_hh1, bf1, bias1);

    // x A-frag base: lane covers row=l15, k = quad*8..+7 (lo) / +32 (hi)
    const size_t xoff = ((size_t)(b0 + l15) * TT) * 64 + quad * 8;

    // prefetch slots (distance 2 steps)
    float4 xfA0, xfA1, xfA2, xfA3, xfB0, xfB1, xfB2, xfB3;

#define ISSUE(t_, S)                                                          \
    if ((t_) < TT) {                                                          \
        const float* p = x + xoff + (size_t)(t_) * 64;                        \
        xf##S##0 = *(const float4*)p;        xf##S##1 = *(const float4*)(p + 4);  \
        xf##S##2 = *(const float4*)(p + 32); xf##S##3 = *(const float4*)(p + 36); \
    }

    // zero all h buffers (h0(-1)=0, h1(-1)=h1(-2)=0)
    for (int i = tid; i < 2 * MM * 72; i += 256) {
        ((ushort*)h0s)[i] = 0;
        ((ushort*)h1s)[i] = 0;
    }

    ISSUE(0, A);
    ISSUE(1, B);

    float c00 = 0.f, c01 = 0.f, c02 = 0.f, c03 = 0.f;   // layer-0 c, rows quad*4+r
    float c10 = 0.f, c11 = 0.f, c12 = 0.f, c13 = 0.f;   // layer-1 c
    BAR();

// one LSTM cell update for row quad*4+R, unit hq; CV is an lvalue scalar
#define CELL(ACC, CV, HDST, R)                                                \
    {                                                                         \
        const float gi = ACC[0][R], gf = ACC[1][R];                           \
        const float gg = ACC[2][R], go = ACC[3][R];                           \
        CV = sigf(gf) * CV + sigf(gi) * tanhf_(gg);                           \
        HDST[quad * 4 + R][hq] = f2bf(sigf(go) * tanhf_(CV));                 \
    }

// step t_: L0 cell(t_) and (if DOL1) L1 cell(t_-1). CUR = t_&1, NXT = CUR^1.
#define STEP(t_, CUR, NXT, S, DOL1)                                           \
    {                                                                         \
        const short8 xlo  = pack8(xf##S##0, xf##S##1);                        \
        const short8 xhi  = pack8(xf##S##2, xf##S##3);                        \
        const short8 h0lo = *(const short8*)&h0s[CUR][l15][quad * 8];         \
        const short8 h0hi = *(const short8*)&h0s[CUR][l15][32 + quad * 8];    \
        short8 h1lo, h1hi;                                                    \
        if (DOL1) {                                                           \
            h1lo = *(const short8*)&h1s[CUR][l15][quad * 8];                  \
            h1hi = *(const short8*)&h1s[CUR][l15][32 + quad * 8];             \
        }                                                                     \
        ISSUE((t_) + 2, S);                                                   \
        f32x4 acc0[4], acc1[4];                                               \
        _Pragma("unroll")                                                     \
        for (int g = 0; g < 4; ++g) {                                         \
            f32x4 a = {bias0[g], bias0[g], bias0[g], bias0[g]};               \
            a = MFMA(xlo,  bf0[g][0], a, 0, 0, 0);                            \
            a = MFMA(xhi,  bf0[g][1], a, 0, 0, 0);                            \
            a = MFMA(h0lo, bf0[g][2], a, 0, 0, 0);                            \
            a = MFMA(h0hi, bf0[g][3], a, 0, 0, 0);                            \
            acc0[g] = a;                                                      \
            if (DOL1) {                                                       \
                f32x4 b = {bias1[g], bias1[g], bias1[g], bias1[g]};           \
                b = MFMA(h0lo, bf1[g][0], b, 0, 0, 0);                        \
                b = MFMA(h0hi, bf1[g][1], b, 0, 0, 0);                        \
                b = MFMA(h1lo, bf1[g][2], b, 0, 0, 0);                        \
                b = MFMA(h1hi, bf1[g][3], b, 0, 0, 0);                        \
                acc1[g] = b;                                                  \
            }                                                                 \
        }                                                                     \
        CELL(acc0, c00, h0s[NXT], 0); CELL(acc0, c01, h0s[NXT], 1);           \
        CELL(acc0, c02, h0s[NXT], 2); CELL(acc0, c03, h0s[NXT], 3);           \
        if (DOL1) {                                                           \
            CELL(acc1, c10, h1s[NXT], 0); CELL(acc1, c11, h1s[NXT], 1);       \
            CELL(acc1, c12, h1s[NXT], 2); CELL(acc1, c13, h1s[NXT], 3);       \
        }                                                                     \
        BAR();                                                                \
    }

    // head peel: L0(0) only
    STEP(0, 0, 1, A, 0)
    // main: steps 1..510 fused
    for (int tb = 1; tb + 1 < TT; tb += 2) {
        STEP(tb,     1, 0, B, 1)
        STEP(tb + 1, 0, 1, A, 1)
    }
    // last fused step: L0(511) + L1(510)
    STEP(TT - 1, 1, 0, B, 1)

    // tail peel: L1(511) from h0(511), h1(510) (both in buffer 0)
    {
        const short8 h0lo = *(const short8*)&h0s[0][l15][quad * 8];
        const short8 h0hi = *(const short8*)&h0s[0][l15][32 + quad * 8];
        const short8 h1lo = *(const short8*)&h1s[0][l15][quad * 8];
        const short8 h1hi = *(const short8*)&h1s[0][l15][32 + quad * 8];
        f32x4 acc1[4];
#pragma unroll
        for (int g = 0; g < 4; ++g) {
            f32x4 b = {bias1[g], bias1[g], bias1[g], bias1[g]};
            b = MFMA(h0lo, bf1[g][0], b, 0, 0, 0);
            b = MFMA(h0hi, bf1[g][1], b, 0, 0, 0);
            b = MFMA(h1lo, bf1[g][2], b, 0, 0, 0);
            b = MFMA(h1hi, bf1[g][3], b, 0, 0, 0);
            acc1[g] = b;
        }
        CELL(acc1, c10, h1s[1], 0); CELL(acc1, c11, h1s[1], 1);
        CELL(acc1, c12, h1s[1], 2); CELL(acc1, c13, h1s[1], 3);
        BAR();
    }
#undef STEP
#undef CELL
#undef ISSUE

    // FC + softplus on h1(T-1) (in h1s[1])
    for (int idx = tid; idx < MM * OO; idx += 256) {
        const int row = idx >> 5, o = idx & 31;
        float a = fc_b[o];
#pragma unroll
        for (int j = 0; j < 64; ++j)
            a = fmaf(fc_w[o * 64 + j], bf2f(h1s[1][row][j]), a);
        out[(size_t)(b0 + row) * OO + o] =
            fmaxf(a, 0.0f) + log1pf(__expf(-fabsf(a)));   // stable softplus
    }
}

extern "C" void kernel_launch(void* const* d_in, const int* in_sizes, int n_in,
                              void* d_out, int out_size, void* d_ws, size_t ws_size,
                              hipStream_t stream) {
    const float* x     = (const float*)d_in[0];
    const float* w_ih0 = (const float*)d_in[1];
    const float* w_hh0 = (const float*)d_in[2];
    const float* b_ih0 = (const float*)d_in[3];
    const float* b_hh0 = (const float*)d_in[4];
    const float* w_ih1 = (const float*)d_in[5];
    const float* w_hh1 = (const float*)d_in[6];
    const float* b_ih1 = (const float*)d_in[7];
    const float* b_hh1 = (const float*)d_in[8];
    const float* fc_w  = (const float*)d_in[9];
    const float* fc_b  = (const float*)d_in[10];
    float* out = (float*)d_out;

    lstm_fused<<<dim3(NBLK), dim3(256), 0, stream>>>(
        x, w_ih0, w_hh0, b_ih0, b_hh0,
        w_ih1, w_hh1, b_ih1, b_hh1, fc_w, fc_b, out);
}

// Round 5
// 586.946 us; speedup vs baseline: 6.5293x; 1.1423x over previous
//
#include <hip/hip_runtime.h>
#include <hip/hip_bf16.h>
#include <math.h>

// (B,T,D,H,O) = (1024, 512, 64, 64, 32)
#define BB 1024
#define TT 512
#define OO 32
#define MM 16              // batch rows per block
#define NBLK (BB/MM)       // 64 blocks

typedef __attribute__((ext_vector_type(8))) short short8;   // 8 bf16 (4 VGPRs)
typedef __attribute__((ext_vector_type(4))) float f32x4;    // MFMA C/D

#define MFMA __builtin_amdgcn_mfma_f32_16x16x32_bf16
#define LOG2E 1.4426950408889634f
#define K2    2.8853900817779268f   /* 2*log2(e) */

// Raw barrier: waits LDS ops only; global loads stay in flight (no vmcnt drain).
#define BAR() asm volatile("s_waitcnt lgkmcnt(0)\n\ts_barrier" ::: "memory")

// raw v_exp_f32 (2^x)
__device__ __forceinline__ float exp2f_(float x) {
#if __has_builtin(__builtin_amdgcn_exp2f)
    return __builtin_amdgcn_exp2f(x);
#else
    float r; asm("v_exp_f32 %0, %1" : "=v"(r) : "v"(x)); return r;
#endif
}

// fp32 -> bf16 RNE (one-time weight conversion)
__device__ __forceinline__ ushort f2bf(float f) {
    union { float f; unsigned u; } v; v.f = f;
    unsigned r = v.u + 0x7FFF + ((v.u >> 16) & 1);
    return (ushort)(r >> 16);
}
__device__ __forceinline__ float bf2f(ushort u) {
    union { unsigned u; float f; } v; v.u = ((unsigned)u) << 16; return v.f;
}
// pack two fp32 -> bf16x2 via v_perm (round-half-up)
__device__ __forceinline__ unsigned pkbf(float a, float b) {
    union { float f; unsigned u; } x, y; x.f = a; y.f = b;
    return __builtin_amdgcn_perm(y.u + 0x8000u, x.u + 0x8000u, 0x07060302u);
}
__device__ __forceinline__ short8 pack8(const float4& a, const float4& b) {
    union { unsigned u[4]; short8 s; } r;
    r.u[0] = pkbf(a.x, a.y); r.u[1] = pkbf(a.z, a.w);
    r.u[2] = pkbf(b.x, b.y); r.u[3] = pkbf(b.z, b.w);
    return r.s;
}

// Fused 2-layer LSTM, layer-per-wave-group. Block = 512 thr = 8 waves owns
// MM=16 batch rows for all T. Waves 0-3: layer-0 cell(t); waves 4-7: layer-1
// cell(t-1) (lag-1 fusion). Each group: 1 layer's weights as MFMA B-frags in
// VGPRs (16 x short8), 4 cells/lane pointwise. 2 waves/SIMD hide each
// other's latency. One raw barrier per step; h0/h1 double-buffered in LDS.
// Gate pre-scales (+-log2e, 2log2e) folded into weights+bias -> raw v_exp.
__global__ __launch_bounds__(512)
void lstm_fused8(const float* __restrict__ x,         // [B][T][64] fp32
                 const float* __restrict__ w_ih0,     // [256][64]
                 const float* __restrict__ w_hh0,     // [256][64]
                 const float* __restrict__ b_ih0,     // [256]
                 const float* __restrict__ b_hh0,     // [256]
                 const float* __restrict__ w_ih1,     // [256][64]
                 const float* __restrict__ w_hh1,     // [256][64]
                 const float* __restrict__ b_ih1,     // [256]
                 const float* __restrict__ b_hh1,     // [256]
                 const float* __restrict__ fc_w,      // [32][64]
                 const float* __restrict__ fc_b,      // [32]
                 float* __restrict__ out)             // [B][32]
{
    // stride 72 ushorts: 16B-aligned rows, max 2-way bank aliasing (free)
    __shared__ ushort h0s[2][MM][72];
    __shared__ ushort h1s[2][MM][72];

    const int tid  = threadIdx.x;
    const int wv   = tid >> 6;           // 0..7
    const bool gB  = (wv >= 4);          // layer-1 group
    const int u    = wv & 3;             // unit group (16 units)
    const int ln   = tid & 63;
    const int l15  = ln & 15;
    const int quad = ln >> 4;
    const int b0   = blockIdx.x * MM;
    const int hq   = 16 * u + l15;       // this lane's h unit column

    // ---- one-time: this group's layer weights as B-frags, scales folded ----
    // B[k][n] frag (16x16x32): lane holds k = quad*8+j, n = l15.
    // K=128: k<64 -> input-weight half, k>=64 -> recurrent half.
    // gate order i,f,g,o; scale: i,f,o -> -log2e (e^-x), g -> +2log2e (e^2g).
    const float* wih = gB ? w_ih1 : w_ih0;
    const float* whh = gB ? w_hh1 : w_hh0;
    const float* bih = gB ? b_ih1 : b_ih0;
    const float* bhh = gB ? b_hh1 : b_hh0;

    short8 bfrag[4][4];
    float  biasv[4];
#pragma unroll
    for (int g = 0; g < 4; ++g) {
        const float sc = (g == 2) ? K2 : -LOG2E;
        const int col = 64 * g + 16 * u + l15;
        biasv[g] = (bih[col] + bhh[col]) * sc;
#pragma unroll
        for (int kt = 0; kt < 4; ++kt) {
            const int kb = kt * 32 + quad * 8;
            const float* src = (kb < 64) ? (wih + col * 64 + kb)
                                         : (whh + col * 64 + (kb - 64));
            const float4 v0 = *(const float4*)src;
            const float4 v1 = *(const float4*)(src + 4);
            short8 b;
            b[0] = (short)f2bf(v0.x * sc); b[1] = (short)f2bf(v0.y * sc);
            b[2] = (short)f2bf(v0.z * sc); b[3] = (short)f2bf(v0.w * sc);
            b[4] = (short)f2bf(v1.x * sc); b[5] = (short)f2bf(v1.y * sc);
            b[6] = (short)f2bf(v1.z * sc); b[7] = (short)f2bf(v1.w * sc);
            bfrag[g][kt] = b;
        }
    }

    // x A-frag base (group A only): row=l15, k = quad*8..+7 (lo) / +32 (hi)
    const size_t xoff = ((size_t)(b0 + l15) * TT) * 64 + quad * 8;
    float4 xfA0, xfA1, xfA2, xfA3, xfB0, xfB1, xfB2, xfB3;

#define ISSUE(t_, S)                                                          \
    if ((t_) < TT) {                                                          \
        const float* p = x + xoff + (size_t)(t_) * 64;                        \
        xf##S##0 = *(const float4*)p;        xf##S##1 = *(const float4*)(p + 4);  \
        xf##S##2 = *(const float4*)(p + 32); xf##S##3 = *(const float4*)(p + 36); \
    }

    // zero both h double-buffers (h0(-1)=0, h1(-1)=h1(-2)=0)
    for (int i = tid; i < 2 * MM * 72; i += 512) {
        ((ushort*)h0s)[i] = 0;
        ((ushort*)h1s)[i] = 0;
    }
    if (!gB) { ISSUE(0, A); ISSUE(1, B); }

    float c0 = 0.f, c1 = 0.f, c2 = 0.f, c3 = 0.f;   // this group's c-states
    BAR();

// one cell: pre-scaled gates -> 5 exp2 + 3 rcp. Overflow-safe: e^{2g},e^{2c}
// clamped; e^{-x}=inf degrades to sigma=0 gracefully.
#define CELL(ACC, CV, HROWS, R)                                               \
    {                                                                         \
        const float yi = ACC[0][R], yf = ACC[1][R];                           \
        const float yg = ACC[2][R], yo = ACC[3][R];                           \
        const float Ef = exp2f_(yf);                                          \
        const float Ei = exp2f_(yi);                                          \
        const float Eg = exp2f_(fminf(yg, 80.f));                             \
        const float sf = __builtin_amdgcn_rcpf(1.f + Ef);                     \
        const float rd = __builtin_amdgcn_rcpf((1.f + Ei) * (1.f + Eg));      \
        CV = sf * CV + (Eg - 1.f) * rd;                                       \
        const float Ec = exp2f_(fminf(CV * K2, 80.f));                        \
        const float Eo = exp2f_(yo);                                          \
        const float r2 = __builtin_amdgcn_rcpf((1.f + Eo) * (1.f + Ec));      \
        union { float f; unsigned uu; } hv; hv.f = (Ec - 1.f) * r2;           \
        HROWS[quad * 4 + R][hq] = (ushort)((hv.uu + 0x8000u) >> 16);          \
    }

// step t_: group A does L0 cell(t_) if DOA; group B does L1 cell(t_-1) if DOB.
#define STEP(t_, CUR, NXT, S, DOA, DOB)                                       \
    {                                                                         \
        if (!gB) {                                                            \
            if (DOA) {                                                        \
                const short8 a2 = *(const short8*)&h0s[CUR][l15][quad * 8];   \
                const short8 a3 = *(const short8*)&h0s[CUR][l15][32 + quad * 8]; \
                const short8 a0 = pack8(xf##S##0, xf##S##1);                  \
                const short8 a1 = pack8(xf##S##2, xf##S##3);                  \
                ISSUE((t_) + 2, S);                                           \
                f32x4 acc[4];                                                 \
                _Pragma("unroll")                                             \
                for (int g = 0; g < 4; ++g) {                                 \
                    f32x4 a = {biasv[g], biasv[g], biasv[g], biasv[g]};       \
                    a = MFMA(a0, bfrag[g][0], a, 0, 0, 0);                    \
                    a = MFMA(a1, bfrag[g][1], a, 0, 0, 0);                    \
                    a = MFMA(a2, bfrag[g][2], a, 0, 0, 0);                    \
                    a = MFMA(a3, bfrag[g][3], a, 0, 0, 0);                    \
                    acc[g] = a;                                               \
                }                                                             \
                CELL(acc, c0, h0s[NXT], 0); CELL(acc, c1, h0s[NXT], 1);       \
                CELL(acc, c2, h0s[NXT], 2); CELL(acc, c3, h0s[NXT], 3);       \
            }                                                                 \
        } else {                                                              \
            if (DOB) {                                                        \
                const short8 a0 = *(const short8*)&h0s[CUR][l15][quad * 8];   \
                const short8 a1 = *(const short8*)&h0s[CUR][l15][32 + quad * 8]; \
                const short8 a2 = *(const short8*)&h1s[CUR][l15][quad * 8];   \
                const short8 a3 = *(const short8*)&h1s[CUR][l15][32 + quad * 8]; \
                f32x4 acc[4];                                                 \
                _Pragma("unroll")                                             \
                for (int g = 0; g < 4; ++g) {                                 \
                    f32x4 a = {biasv[g], biasv[g], biasv[g], biasv[g]};       \
                    a = MFMA(a0, bfrag[g][0], a, 0, 0, 0);                    \
                    a = MFMA(a1, bfrag[g][1], a, 0, 0, 0);                    \
                    a = MFMA(a2, bfrag[g][2], a, 0, 0, 0);                    \
                    a = MFMA(a3, bfrag[g][3], a, 0, 0, 0);                    \
                    acc[g] = a;                                               \
                }                                                             \
                CELL(acc, c0, h1s[NXT], 0); CELL(acc, c1, h1s[NXT], 1);       \
                CELL(acc, c2, h1s[NXT], 2); CELL(acc, c3, h1s[NXT], 3);       \
            }                                                                 \
        }                                                                     \
        BAR();                                                                \
    }

    // head: L0(0) only
    STEP(0, 0, 1, A, 1, 0)
    // main: t = 1..510
    for (int tb = 1; tb + 2 < TT; tb += 2) {
        STEP(tb,     1, 0, B, 1, 1)
        STEP(tb + 1, 0, 1, A, 1, 1)
    }
    // t = 511: L0(511) + L1(510)
    STEP(TT - 1, 1, 0, B, 1, 1)
    // tail t = 512: L1(511) only -> h1s[1]
    STEP(TT, 0, 1, A, 0, 1)
#undef STEP
#undef CELL
#undef ISSUE

    // FC + softplus on h1(T-1) (in h1s[1]); 512 outputs, one per thread
    {
        const int row = tid >> 5, o = tid & 31;
        float a = fc_b[o];
#pragma unroll
        for (int j = 0; j < 64; ++j)
            a = fmaf(fc_w[o * 64 + j], bf2f(h1s[1][row][j]), a);
        out[(size_t)(b0 + row) * OO + o] =
            fmaxf(a, 0.0f) + log1pf(__expf(-fabsf(a)));   // stable softplus
    }
}

extern "C" void kernel_launch(void* const* d_in, const int* in_sizes, int n_in,
                              void* d_out, int out_size, void* d_ws, size_t ws_size,
                              hipStream_t stream) {
    const float* x     = (const float*)d_in[0];
    const float* w_ih0 = (const float*)d_in[1];
    const float* w_hh0 = (const float*)d_in[2];
    const float* b_ih0 = (const float*)d_in[3];
    const float* b_hh0 = (const float*)d_in[4];
    const float* w_ih1 = (const float*)d_in[5];
    const float* w_hh1 = (const float*)d_in[6];
    const float* b_ih1 = (const float*)d_in[7];
    const float* b_hh1 = (const float*)d_in[8];
    const float* fc_w  = (const float*)d_in[9];
    const float* fc_b  = (const float*)d_in[10];
    float* out = (float*)d_out;

    lstm_fused8<<<dim3(NBLK), dim3(512), 0, stream>>>(
        x, w_ih0, w_hh0, b_ih0, b_hh0,
        w_ih1, w_hh1, b_ih1, b_hh1, fc_w, fc_b, out);
}

// Round 6
// 556.938 us; speedup vs baseline: 6.8811x; 1.0539x over previous
//
#include <hip/hip_runtime.h>
#include <hip/hip_bf16.h>
#include <math.h>

// (B,T,D,H,O) = (1024, 512, 64, 64, 32)
#define BB 1024
#define TT 512
#define OO 32
#define MM 4               // batch rows per block
#define NBLK (BB/MM)       // 256 blocks -> all 256 CUs

typedef __attribute__((ext_vector_type(8))) short short8;   // 8 bf16 (4 VGPRs)
typedef __attribute__((ext_vector_type(4))) float f32x4;    // MFMA C/D

#define MFMA __builtin_amdgcn_mfma_f32_16x16x32_bf16
#define LOG2E 1.4426950408889634f
#define K2    2.8853900817779268f   /* 2*log2(e) */

// Raw barrier: waits LDS ops only; global loads stay in flight (no vmcnt drain).
#define BAR() asm volatile("s_waitcnt lgkmcnt(0)\n\ts_barrier" ::: "memory")

// raw v_exp_f32 (2^x)
__device__ __forceinline__ float exp2f_(float x) {
#if __has_builtin(__builtin_amdgcn_exp2f)
    return __builtin_amdgcn_exp2f(x);
#else
    float r; asm("v_exp_f32 %0, %1" : "=v"(r) : "v"(x)); return r;
#endif
}

// fp32 -> bf16 RNE (one-time weight conversion)
__device__ __forceinline__ ushort f2bf(float f) {
    union { float f; unsigned u; } v; v.f = f;
    unsigned r = v.u + 0x7FFF + ((v.u >> 16) & 1);
    return (ushort)(r >> 16);
}
__device__ __forceinline__ float bf2f(ushort u) {
    union { unsigned u; float f; } v; v.u = ((unsigned)u) << 16; return v.f;
}
// pack two fp32 -> bf16x2 via v_perm (round-half-up)
__device__ __forceinline__ unsigned pkbf(float a, float b) {
    union { float f; unsigned u; } x, y; x.f = a; y.f = b;
    return __builtin_amdgcn_perm(y.u + 0x8000u, x.u + 0x8000u, 0x07060302u);
}
__device__ __forceinline__ short8 pack8(const float4& a, const float4& b) {
    union { unsigned u[4]; short8 s; } r;
    r.u[0] = pkbf(a.x, a.y); r.u[1] = pkbf(a.z, a.w);
    r.u[2] = pkbf(b.x, b.y); r.u[3] = pkbf(b.z, b.w);
    return r.s;
}

// Fused 2-layer LSTM, 4 batch rows/block across 256 blocks (all CUs).
// Block = 512 thr = 8 waves. Waves 0-3: layer-0 cell(t); waves 4-7: layer-1
// cell(t-1) (lag-1 fusion). M=16 MFMA tile with rows 4-15 zero (waste is
// cheap); after GEMM, quad-0 lanes (which hold rows 0-3) spill the 4 gate
// f32x4's to per-wave LDS and EVERY lane does exactly ONE cell (row=quad,
// unit=l15) -> 8 trans/lane/step instead of 32. Intra-wave redistribution:
// no extra barrier. L0's x-part MFMAs precomputed before the barrier.
__global__ __launch_bounds__(512)
void lstm_f256(const float* __restrict__ x,         // [B][T][64] fp32
               const float* __restrict__ w_ih0,     // [256][64]
               const float* __restrict__ w_hh0,     // [256][64]
               const float* __restrict__ b_ih0,     // [256]
               const float* __restrict__ b_hh0,     // [256]
               const float* __restrict__ w_ih1,     // [256][64]
               const float* __restrict__ w_hh1,     // [256][64]
               const float* __restrict__ b_ih1,     // [256]
               const float* __restrict__ b_hh1,     // [256]
               const float* __restrict__ fc_w,      // [32][64]
               const float* __restrict__ fc_b,      // [32]
               float* __restrict__ out)             // [B][32]
{
    // h buffers: 16 rows allocated (A-frag reads l15=0..15); rows 4-15 stay 0.
    // stride 72 ushorts: 16B-aligned rows, max 2-way bank aliasing (free)
    __shared__ ushort h0s[2][16][72];
    __shared__ ushort h1s[2][16][72];
    __shared__ float  gsh[8][4][16][4];   // [wave][gate][unit l15][row]

    const int tid  = threadIdx.x;
    const int wv   = tid >> 6;           // 0..7
    const bool gB  = (wv >= 4);          // layer-1 group
    const int u    = wv & 3;             // unit block (16 units)
    const int ln   = tid & 63;
    const int l15  = ln & 15;
    const int quad = ln >> 4;
    const int b0   = blockIdx.x * MM;
    const int hq   = 16 * u + l15;       // this lane's cell unit column

    // ---- one-time: this group's layer weights as B-frags, exp2-scales folded
    // B[k][n] frag (16x16x32): lane holds k = quad*8+j, n = l15.
    // K=128: k<64 -> input half (x or h0), k>=64 -> recurrent half.
    // gate order i,f,g,o; scale: i,f,o -> -log2e (e^-x), g -> +2log2e (e^2g).
    const float* wih = gB ? w_ih1 : w_ih0;
    const float* whh = gB ? w_hh1 : w_hh0;
    const float* bih = gB ? b_ih1 : b_ih0;
    const float* bhh = gB ? b_hh1 : b_hh0;

    short8 bfrag[4][4];
    f32x4  bias4[4];
#pragma unroll
    for (int g = 0; g < 4; ++g) {
        const float sc = (g == 2) ? K2 : -LOG2E;
        const int col = 64 * g + 16 * u + l15;
        const float bv = (bih[col] + bhh[col]) * sc;
        bias4[g] = (f32x4){bv, bv, bv, bv};
#pragma unroll
        for (int kt = 0; kt < 4; ++kt) {
            const int kb = kt * 32 + quad * 8;
            const float* src = (kb < 64) ? (wih + col * 64 + kb)
                                         : (whh + col * 64 + (kb - 64));
            const float4 v0 = *(const float4*)src;
            const float4 v1 = *(const float4*)(src + 4);
            short8 b;
            b[0] = (short)f2bf(v0.x * sc); b[1] = (short)f2bf(v0.y * sc);
            b[2] = (short)f2bf(v0.z * sc); b[3] = (short)f2bf(v0.w * sc);
            b[4] = (short)f2bf(v1.x * sc); b[5] = (short)f2bf(v1.y * sc);
            b[6] = (short)f2bf(v1.z * sc); b[7] = (short)f2bf(v1.w * sc);
            bfrag[g][kt] = b;
        }
    }

    // x A-frag base (L0 waves): row = l15 clamped to MM-1 (lanes 4-15 reread
    // row 3 -> same cache lines, no extra HBM), k = quad*8..+7 / +32
    const int xr = (l15 < MM) ? l15 : (MM - 1);
    const size_t xoff = ((size_t)(b0 + xr) * TT) * 64 + quad * 8;
    float4 xfA0, xfA1, xfA2, xfA3, xfB0, xfB1, xfB2, xfB3;
    f32x4 pre[4];

#define ISSUE(t_, S)                                                          \
    if ((t_) < TT) {                                                          \
        const float* p = x + xoff + (size_t)(t_) * 64;                        \
        xf##S##0 = *(const float4*)p;        xf##S##1 = *(const float4*)(p + 4);  \
        xf##S##2 = *(const float4*)(p + 32); xf##S##3 = *(const float4*)(p + 36); \
    }

    // zero both h double-buffers (rows 4-15 stay zero forever)
    for (int i = tid; i < 2 * 16 * 72; i += 512) {
        ((ushort*)h0s)[i] = 0;
        ((ushort*)h1s)[i] = 0;
    }

    float cc = 0.f;   // this lane's single cell state
    if (!gB) {
        ISSUE(0, A);
        ISSUE(1, B);
        // pre(0) = bias + x(0) @ W_ih  (x-part of step 0)
        const short8 xlo = pack8(xfA0, xfA1);
        const short8 xhi = pack8(xfA2, xfA3);
#pragma unroll
        for (int g = 0; g < 4; ++g)
            pre[g] = MFMA(xhi, bfrag[g][1],
                          MFMA(xlo, bfrag[g][0], bias4[g], 0, 0, 0), 0, 0, 0);
    }
    BAR();

// one cell from this wave's gate LDS: 5 exp2 + 3 rcp, overflow-clamped
#define CELL1(HD, NXT)                                                        \
    {                                                                         \
        const float yi = gsh[wv][0][l15][quad];                               \
        const float yf = gsh[wv][1][l15][quad];                               \
        const float yg = gsh[wv][2][l15][quad];                               \
        const float yo = gsh[wv][3][l15][quad];                               \
        const float Ef = exp2f_(yf);                                          \
        const float Ei = exp2f_(yi);                                          \
        const float Eg = exp2f_(fminf(yg, 80.f));                             \
        const float sf = __builtin_amdgcn_rcpf(1.f + Ef);                     \
        const float rd = __builtin_amdgcn_rcpf((1.f + Ei) * (1.f + Eg));      \
        cc = sf * cc + (Eg - 1.f) * rd;                                       \
        const float Ec = exp2f_(fminf(cc * K2, 80.f));                        \
        const float Eo = exp2f_(yo);                                          \
        const float r2 = __builtin_amdgcn_rcpf((1.f + Eo) * (1.f + Ec));      \
        union { float f; unsigned uu; } hv; hv.f = (Ec - 1.f) * r2;           \
        HD[NXT][quad][hq] = (ushort)((hv.uu + 0x8000u) >> 16);                \
    }

// step t_: L0 cell(t_) if DOA; L1 cell(t_-1) if DOB. USE = x(t_+1) slot for
// next pre; LD = slot to prefetch x(t_+2) into.
#define STEP(t_, CUR, NXT, USE, LD, DOA, DOB)                                 \
    {                                                                         \
        if (!gB) {                                                            \
            if (DOA) {                                                        \
                const short8 a2 = *(const short8*)&h0s[CUR][l15][quad * 8];   \
                const short8 a3 = *(const short8*)&h0s[CUR][l15][32 + quad * 8]; \
                f32x4 acc[4];                                                 \
                _Pragma("unroll")                                             \
                for (int g = 0; g < 4; ++g)                                   \
                    acc[g] = MFMA(a3, bfrag[g][3],                            \
                                  MFMA(a2, bfrag[g][2], pre[g], 0,0,0), 0,0,0); \
                if (quad == 0) {                                              \
                    _Pragma("unroll")                                         \
                    for (int g = 0; g < 4; ++g)                               \
                        *(f32x4*)&gsh[wv][g][l15][0] = acc[g];                \
                }                                                             \
                ISSUE((t_) + 2, LD);                                          \
                CELL1(h0s, NXT);                                              \
                if ((t_) + 1 < TT) {                                          \
                    const short8 xlo = pack8(xf##USE##0, xf##USE##1);         \
                    const short8 xhi = pack8(xf##USE##2, xf##USE##3);         \
                    _Pragma("unroll")                                         \
                    for (int g = 0; g < 4; ++g)                               \
                        pre[g] = MFMA(xhi, bfrag[g][1],                       \
                                      MFMA(xlo, bfrag[g][0], bias4[g], 0,0,0), 0,0,0); \
                }                                                             \
            }                                                                 \
        } else {                                                              \
            if (DOB) {                                                        \
                const short8 a0 = *(const short8*)&h0s[CUR][l15][quad * 8];   \
                const short8 a1 = *(const short8*)&h0s[CUR][l15][32 + quad * 8]; \
                const short8 a2 = *(const short8*)&h1s[CUR][l15][quad * 8];   \
                const short8 a3 = *(const short8*)&h1s[CUR][l15][32 + quad * 8]; \
                f32x4 acc[4];                                                 \
                _Pragma("unroll")                                             \
                for (int g = 0; g < 4; ++g) {                                 \
                    f32x4 a = bias4[g];                                       \
                    a = MFMA(a0, bfrag[g][0], a, 0, 0, 0);                    \
                    a = MFMA(a1, bfrag[g][1], a, 0, 0, 0);                    \
                    a = MFMA(a2, bfrag[g][2], a, 0, 0, 0);                    \
                    a = MFMA(a3, bfrag[g][3], a, 0, 0, 0);                    \
                    acc[g] = a;                                               \
                }                                                             \
                if (quad == 0) {                                              \
                    _Pragma("unroll")                                         \
                    for (int g = 0; g < 4; ++g)                               \
                        *(f32x4*)&gsh[wv][g][l15][0] = acc[g];                \
                }                                                             \
                CELL1(h1s, NXT);                                              \
            }                                                                 \
        }                                                                     \
        BAR();                                                                \
    }

    // head: L0(0) only
    STEP(0, 0, 1, B, A, 1, 0)
    // main: t = 1..510
    for (int tb = 1; tb + 2 < TT; tb += 2) {
        STEP(tb,     1, 0, A, B, 1, 1)
        STEP(tb + 1, 0, 1, B, A, 1, 1)
    }
    // t = 511: L0(511) + L1(510)
    STEP(TT - 1, 1, 0, A, B, 1, 1)
    // tail t = 512: L1(511) only -> h1s[1]
    STEP(TT, 0, 1, B, A, 0, 1)
#undef STEP
#undef CELL1
#undef ISSUE

    // FC + softplus on h1(T-1) (rows 0-3 of h1s[1]); 128 outputs
    if (tid < MM * OO) {
        const int row = tid >> 5, o = tid & 31;
        float a = fc_b[o];
#pragma unroll
        for (int j = 0; j < 64; ++j)
            a = fmaf(fc_w[o * 64 + j], bf2f(h1s[1][row][j]), a);
        out[(size_t)(b0 + row) * OO + o] =
            fmaxf(a, 0.0f) + log1pf(__expf(-fabsf(a)));   // stable softplus
    }
}

extern "C" void kernel_launch(void* const* d_in, const int* in_sizes, int n_in,
                              void* d_out, int out_size, void* d_ws, size_t ws_size,
                              hipStream_t stream) {
    const float* x     = (const float*)d_in[0];
    const float* w_ih0 = (const float*)d_in[1];
    const float* w_hh0 = (const float*)d_in[2];
    const float* b_ih0 = (const float*)d_in[3];
    const float* b_hh0 = (const float*)d_in[4];
    const float* w_ih1 = (const float*)d_in[5];
    const float* w_hh1 = (const float*)d_in[6];
    const float* b_ih1 = (const float*)d_in[7];
    const float* b_hh1 = (const float*)d_in[8];
    const float* fc_w  = (const float*)d_in[9];
    const float* fc_b  = (const float*)d_in[10];
    float* out = (float*)d_out;

    lstm_f256<<<dim3(NBLK), dim3(512), 0, stream>>>(
        x, w_ih0, w_hh0, b_ih0, b_hh0,
        w_ih1, w_hh1, b_ih1, b_hh1, fc_w, fc_b, out);
}